// Round 1
// baseline (63.911 us; speedup 1.0000x reference)
//
#include <hip/hip_runtime.h>

// LIF "RepeatEncoder": input (B,L,C) f32, output spikes (T,B,C,L) f32.
// Per element a = in[b,l,c], v starts at 0; per t: v = v + (a - v)*0.5;
// s = (v >= 1); v = s ? 0 : v. Output out[t,b,c,l] = s.
// Time-constant input => each thread runs the 16-step recurrence privately.

#define T_STEPS 16
#define B 64
#define L 512
#define C 128

__global__ __launch_bounds__(256) void lif_repeat_kernel(const float* __restrict__ in,
                                                         float* __restrict__ out) {
    // One thread per (b, c, l4) where l4 indexes groups of 4 consecutive l.
    // Total threads = B * C * (L/4) = 64*128*128 = 1,048,576 = 4096 blocks x 256.
    const int tid = blockIdx.x * blockDim.x + threadIdx.x;
    const int l4 = tid & (L / 4 - 1);          // 7 bits
    const int c  = (tid >> 7) & (C - 1);       // 7 bits
    const int b  = tid >> 14;                  // 6 bits
    const int l  = l4 * 4;

    // Strided input reads (stride C floats); total read volume is small (16.8 MB),
    // L2/L3 absorb the re-reads across c.
    const float* inp = in + ((size_t)(b * L + l)) * C + c;
    const float a0 = inp[0 * C];
    const float a1 = inp[1 * C];
    const float a2 = inp[2 * C];
    const float a3 = inp[3 * C];

    float v0 = 0.f, v1 = 0.f, v2 = 0.f, v3 = 0.f;

    // Output base for t=0; planes are B*C*L floats apart.
    float* outp = out + ((size_t)(b * C + c)) * L + l;
    const size_t plane = (size_t)B * C * L;

#pragma unroll
    for (int t = 0; t < T_STEPS; ++t) {
        // Exact replication of reference arithmetic: v = v + (x - v)/2
        v0 = v0 + (a0 - v0) * 0.5f;
        v1 = v1 + (a1 - v1) * 0.5f;
        v2 = v2 + (a2 - v2) * 0.5f;
        v3 = v3 + (a3 - v3) * 0.5f;

        const float s0 = (v0 >= 1.0f) ? 1.0f : 0.0f;
        const float s1 = (v1 >= 1.0f) ? 1.0f : 0.0f;
        const float s2 = (v2 >= 1.0f) ? 1.0f : 0.0f;
        const float s3 = (v3 >= 1.0f) ? 1.0f : 0.0f;

        // Hard reset to 0 on spike.
        v0 = (s0 != 0.0f) ? 0.0f : v0;
        v1 = (s1 != 0.0f) ? 0.0f : v1;
        v2 = (s2 != 0.0f) ? 0.0f : v2;
        v3 = (s3 != 0.0f) ? 0.0f : v3;

        // Coalesced 16B/lane store: consecutive tid -> consecutive l.
        float4 s = make_float4(s0, s1, s2, s3);
        *reinterpret_cast<float4*>(outp + (size_t)t * plane) = s;
    }
}

extern "C" void kernel_launch(void* const* d_in, const int* in_sizes, int n_in,
                              void* d_out, int out_size, void* d_ws, size_t ws_size,
                              hipStream_t stream) {
    const float* in = (const float*)d_in[0];
    float* out = (float*)d_out;

    const int total_threads = B * C * (L / 4);   // 1,048,576
    const int block = 256;
    const int grid = total_threads / block;      // 4096

    hipLaunchKernelGGL(lif_repeat_kernel, dim3(grid), dim3(block), 0, stream, in, out);
}

// Round 2
// 57.516 us; speedup vs baseline: 1.1112x; 1.1112x over previous
//
#include <hip/hip_runtime.h>

// LIF "RepeatEncoder": input (B,L,C) f32, output spikes (T,B,C,L) f32.
// v=0; per t: v = v + (a - v)*0.5; s = (v >= 1); v = s ? 0 : v; out[t,b,c,l] = s.
// Input is time-constant, so each thread runs the 16-step recurrence privately.
//
// Round-2 change: LDS tile transpose. Each block owns a disjoint (32 l x 32 c)
// tile of one b. Input loads are fully coalesced (128B segments), staged in LDS,
// then threads re-map to (c, l-group-of-4) so the dominant writes stay float4-
// coalesced along l. Nontemporal stores keep the 1GB write stream out of L2.

#define T_STEPS 16
#define B 64
#define L 512
#define C 128
#define LT 32   // l-tile
#define CT 32   // c-tile

typedef float v4f __attribute__((ext_vector_type(4)));

__global__ __launch_bounds__(256) void lif_repeat_kernel(const float* __restrict__ in,
                                                         float* __restrict__ out) {
    __shared__ float lds[LT][CT + 1];   // +1 pad: conflict-free transposed reads

    const int blk = blockIdx.x;                 // 4096 blocks
    const int c0 = (blk & 3) * CT;              // 4 c-tiles
    const int l0 = ((blk >> 2) & 15) * LT;      // 16 l-tiles
    const int b  = blk >> 6;                    // 64 b
    const int tid = threadIdx.x;

    // Cooperative coalesced load of the 32x32 tile: in[b, l0+r, c0+cc].
    // Lanes sweep cc fastest -> 128B contiguous per row segment.
    const float* inb = in + ((size_t)(b * L + l0)) * C + c0;
#pragma unroll
    for (int k = 0; k < 4; ++k) {
        const int e  = tid + 256 * k;   // 0..1023
        const int r  = e >> 5;          // l-row 0..31
        const int cc = e & 31;          // c    0..31
        lds[r][cc] = inb[(size_t)r * C + cc];
    }
    __syncthreads();

    // Compute mapping: lane sweeps l-group fastest so stores coalesce along l.
    const int lgrp = tid & 7;       // 8 groups of 4 l
    const int c    = tid >> 3;      // 0..31
    const int l    = lgrp * 4;

    // Transposed LDS reads; pad makes these max 2-way (free).
    const float a0 = lds[l + 0][c];
    const float a1 = lds[l + 1][c];
    const float a2 = lds[l + 2][c];
    const float a3 = lds[l + 3][c];

    float v0 = 0.f, v1 = 0.f, v2 = 0.f, v3 = 0.f;

    float* outp = out + ((size_t)(b * C + c0 + c)) * L + l0 + l;
    const size_t plane = (size_t)B * C * L;

#pragma unroll
    for (int t = 0; t < T_STEPS; ++t) {
        // Exact replication of reference arithmetic: v = v + (x - v)/2.
        // (x-v)*0.5 is exact, so FMA contraction cannot change bits.
        v0 = v0 + (a0 - v0) * 0.5f;
        v1 = v1 + (a1 - v1) * 0.5f;
        v2 = v2 + (a2 - v2) * 0.5f;
        v3 = v3 + (a3 - v3) * 0.5f;

        const float s0 = (v0 >= 1.0f) ? 1.0f : 0.0f;
        const float s1 = (v1 >= 1.0f) ? 1.0f : 0.0f;
        const float s2 = (v2 >= 1.0f) ? 1.0f : 0.0f;
        const float s3 = (v3 >= 1.0f) ? 1.0f : 0.0f;

        v0 = (s0 != 0.0f) ? 0.0f : v0;
        v1 = (s1 != 0.0f) ? 0.0f : v1;
        v2 = (s2 != 0.0f) ? 0.0f : v2;
        v3 = (s3 != 0.0f) ? 0.0f : v3;

        v4f s = (v4f){s0, s1, s2, s3};
        __builtin_nontemporal_store(s, (v4f*)(outp + (size_t)t * plane));
    }
}

extern "C" void kernel_launch(void* const* d_in, const int* in_sizes, int n_in,
                              void* d_out, int out_size, void* d_ws, size_t ws_size,
                              hipStream_t stream) {
    const float* in = (const float*)d_in[0];
    float* out = (float*)d_out;

    const int grid = B * (L / LT) * (C / CT);   // 64*16*4 = 4096
    hipLaunchKernelGGL(lif_repeat_kernel, dim3(grid), dim3(256), 0, stream, in, out);
}